// Round 4
// baseline (569.905 us; speedup 1.0000x reference)
//
#include <hip/hip_runtime.h>
#include <hip/hip_bf16.h>

typedef __hip_bfloat16 bf16;
typedef __attribute__((ext_vector_type(8))) short frag8;   // 8 bf16 = 4 VGPR
typedef __attribute__((ext_vector_type(4))) float frag4f;  // MFMA C/D
typedef __attribute__((ext_vector_type(4))) short short4v; // 8B packed store

#define BB 8
#define HH 16
#define NTOK 2048
#define DD 64
#define HID 256
#define NIT 4
#define CH 512
#define NP 128
#define INV_CD 3.0517578125e-05f  // 1/(CH*DD)

#define MFMA(a,b,c) __builtin_amdgcn_mfma_f32_16x16x32_bf16((a),(b),(c),0,0,0)

// XOR swizzle: spreads 8-row-strided column reads across disjoint 8-bank
// windows (row stride 528B === 0 mod 128B otherwise -> 8-way conflict).
// Keeps frag8 16B alignment (toggles col bits 4-5 only).
#define SW(row,col) ((col) ^ ((((row)>>3)&3)<<4))

__device__ __forceinline__ short f2b(float f){
    union { __hip_bfloat16 b; short s; } u;
    u.b = __float2bfloat16(f);
    return u.s;
}

// Fast tanh via hardware exp: t = 1 - 2/(e^{2u}+1). Stable at +/-inf.
__device__ __forceinline__ float tanh_fast(float u){
    float e = __expf(2.0f*u);
    return 1.0f - 2.0f/(e+1.0f);
}

__device__ __forceinline__ float gelu_f(float x){
    const float c0 = 0.7978845608028654f, c1 = 0.044715f;
    float u = c0*(x + c1*x*x*x);
    float t = tanh_fast(u);
    return 0.5f*x*(1.0f+t);
}

// Fused gelu value + grad: ONE tanh shared.
__device__ __forceinline__ void gelu_both(float x, float* hv, float* gp){
    const float c0 = 0.7978845608028654f, c1 = 0.044715f;
    float x2 = x*x;
    float u = c0*(x + c1*x2*x);
    float t = tanh_fast(u);
    *hv = 0.5f*x*(1.0f+t);
    *gp = 0.5f*(1.0f+t) + 0.5f*x*(1.0f-t*t)*c0*(1.0f+3.0f*c1*x2);
}

// One fused inner-loop iteration. Block = (pair p, token-half). 1024 threads,
// 16 waves (4 row-strips x 4 column-groups). hl/W2c XOR-swizzled (conflict-free
// strided column reads in P3/P4). Per-mt global loads hoisted across barriers.
__global__ __launch_bounds__(1024) void k_step(
    const float* __restrict__ kin, const float* __restrict__ vin,
    const float* __restrict__ MoW1, const float* __restrict__ MoW2,
    const float* __restrict__ Pin,  float* __restrict__ Mnew,
    float* __restrict__ Pout, int hIdx, int fold, int t)
{
    int p = blockIdx.x >> 1, half = blockIdx.x & 1;
    int tid = threadIdx.x;
    int w = tid >> 6, lane = tid & 63, q = lane >> 4, ln = lane & 15;
    int s = w >> 2, ch = w & 3;   // row-strip (16 rows), column quarter

    // 156 KB total -> 1 block/CU
    __shared__ __attribute__((aligned(16))) short W1c[256*72];   // W1^T [e'][d]
    __shared__ __attribute__((aligned(16))) short W2c[64*264];   // W2^T [o][e'] (swz)
    __shared__ __attribute__((aligned(16))) short hl [64*264];   // h  [m][e'] (swz)
    __shared__ __attribute__((aligned(16))) short el [64*72];    // e  [m][o]
    __shared__ __attribute__((aligned(16))) short eTl[64*72];    // e^T [o][m]
    __shared__ __attribute__((aligned(16))) short dzTl[256*72];  // dz^T [e'][m]

    // ---- cast masters -> LDS bf16 (+ fold partials, + materialize Mnew) ----
    {
        int widx = hIdx ? (p & 15) : p;
        const float* w1o = MoW1 + (size_t)widx*16384;
        const float* w2o = MoW2 + (size_t)widx*16384;
        const float* pa = Pin + (size_t)p*32768;
        const float* pb = Pin + (size_t)(NP+p)*32768;
        float* mn1 = Mnew + (size_t)p*16384;
        float* mn2 = Mnew + (size_t)(NP+p)*16384;
        #pragma unroll 4
        for (int i=0;i<16;i++){
            int src = i*1024 + tid;
            float a = w1o[src];
            float b = w2o[src];
            if (fold){
                a -= pa[src] + pb[src];
                b -= pa[16384+src] + pb[16384+src];
            }
            mn1[src] = a;
            mn2[src] = b;
            W1c[(src & 255)*72  + (src >> 8)] = f2b(a);              // [e'][d]
            W2c[(src & 63)*264  + SW(src & 63, src >> 6)] = f2b(b);  // [o][e'] swz
        }
    }
    __syncthreads();

    frag4f dw1[4], dw2[4];
    #pragma unroll
    for (int i=0;i<4;i++){ frag4f zz = {0.f,0.f,0.f,0.f}; dw1[i]=zz; dw2[i]=zz; }

    size_t rowbase = (size_t)p*NTOK + (size_t)t*CH + (size_t)half*256;

    #pragma unroll 1
    for (int mt=0; mt<4; ++mt){
        int m0 = mt*64;

        // ---------- P1: z = x@W1 ; h=gelu(z)->hl ; zacc := gelu'(z) ----------
        frag8 af[2];
        {
            const float* xb = kin + (rowbase + m0 + s*16 + ln)*DD;
            #pragma unroll
            for (int kk=0;kk<2;kk++){
                const float* xr = xb + kk*32 + q*8;
                float4 u0 = *(const float4*)xr;
                float4 u1 = *(const float4*)(xr+4);
                frag8 a;
                a[0]=f2b(u0.x); a[1]=f2b(u0.y); a[2]=f2b(u0.z); a[3]=f2b(u0.w);
                a[4]=f2b(u1.x); a[5]=f2b(u1.y); a[6]=f2b(u1.z); a[7]=f2b(u1.w);
                af[kk]=a;
            }
        }
        // hoisted: y for P2 (hidden under P1 MFMA + gelu)
        float yv[4];
        #pragma unroll
        for (int r=0;r<4;r++)
            yv[r] = vin[(rowbase + m0 + s*16 + q*4 + r)*DD + ch*16 + ln];

        frag4f zacc[4];
        #pragma unroll
        for (int nti=0;nti<4;nti++){
            frag4f zc = {0.f,0.f,0.f,0.f};
            #pragma unroll
            for (int kk=0;kk<2;kk++){
                frag8 b = *(const frag8*)&W1c[((ch*4+nti)*16+ln)*72 + kk*32 + q*8];
                zc = MFMA(af[kk], b, zc);
            }
            zacc[nti] = zc;
        }
        #pragma unroll
        for (int nti=0;nti<4;nti++)
            #pragma unroll
            for (int r=0;r<4;r++){
                float hv, gp;
                gelu_both(zacc[nti][r], &hv, &gp);
                int row = s*16+q*4+r;
                hl[row*264 + SW(row, (ch*4+nti)*16 + ln)] = f2b(hv);
                zacc[nti][r] = gp;
            }
        __syncthreads();

        // ---------- P2: out = h@W2 ; e=(out-y)*s -> el,eTl ----------
        {
            // hoisted: x columns for P4 (hidden under P2+P3)
            float xc[16];
            #pragma unroll
            for (int kk2=0;kk2<2;kk2++)
                #pragma unroll
                for (int j=0;j<8;j++)
                    xc[kk2*8+j] = kin[(rowbase + m0 + kk2*32 + q*8 + j)*DD + s*16 + ln];

            frag8 hfr[8];
            #pragma unroll
            for (int kk=0;kk<8;kk++)
                hfr[kk] = *(const frag8*)&hl[(s*16+ln)*264 + SW(s*16+ln, kk*32 + q*8)];
            frag4f oc = {0.f,0.f,0.f,0.f};
            #pragma unroll
            for (int kk=0;kk<8;kk++){
                frag8 b = *(const frag8*)&W2c[(ch*16+ln)*264 + SW(ch*16+ln, kk*32 + q*8)];
                oc = MFMA(hfr[kk], b, oc);
            }
            short4v ep;
            #pragma unroll
            for (int r=0;r<4;r++){
                float e = (oc[r]-yv[r])*INV_CD;
                el[(s*16+q*4+r)*72 + ch*16 + ln] = f2b(e);
                ep[r] = f2b(e);
            }
            *(short4v*)&eTl[(ch*16+ln)*72 + s*16 + q*4] = ep;
            __syncthreads();

            // ---------- P3: dz = (e@W2^T) * gelu'(z) -> dzTl ----------
            frag8 efr[2];
            #pragma unroll
            for (int kk=0;kk<2;kk++)
                efr[kk] = *(const frag8*)&el[(s*16+ln)*72 + kk*32 + q*8];
            #pragma unroll
            for (int nti=0;nti<4;nti++){
                int nt = ch*4 + nti;
                frag4f dc = {0.f,0.f,0.f,0.f};
                #pragma unroll
                for (int kk=0;kk<2;kk++){
                    frag8 b;
                    #pragma unroll
                    for (int j=0;j<8;j++){
                        int row = kk*32+q*8+j;
                        b[j] = W2c[row*264 + SW(row, nt*16 + ln)];  // conflict-free
                    }
                    dc = MFMA(efr[kk], b, dc);
                }
                short4v dp;
                #pragma unroll
                for (int r=0;r<4;r++)
                    dp[r] = f2b(dc[r]*zacc[nti][r]);
                *(short4v*)&dzTl[(nt*16+ln)*72 + s*16 + q*4] = dp;
            }
            __syncthreads();

            // ---------- P4: dW1 += x^T@dz ; dW2 += h^T@e ----------
            #pragma unroll
            for (int kk2=0;kk2<2;kk2++){
                frag8 a;
                #pragma unroll
                for (int j=0;j<8;j++)
                    a[j] = f2b(xc[kk2*8+j]);
                #pragma unroll
                for (int nti=0;nti<4;nti++){
                    frag8 b = *(const frag8*)&dzTl[((ch*4+nti)*16+ln)*72 + kk2*32 + q*8];
                    dw1[nti] = MFMA(a, b, dw1[nti]);
                }
            }
            #pragma unroll
            for (int kk2=0;kk2<2;kk2++){
                frag8 a;
                #pragma unroll
                for (int j=0;j<8;j++){
                    int row = kk2*32+q*8+j;
                    a[j] = hl[row*264 + SW(row, w*16 + ln)];        // conflict-free
                }
                #pragma unroll
                for (int ot=0;ot<4;ot++){
                    frag8 b = *(const frag8*)&eTl[(ot*16+ln)*72 + kk2*32 + q*8];
                    dw2[ot] = MFMA(a, b, dw2[ot]);
                }
            }
        }
        __syncthreads();
    }

    // ---- write partial dW (non-atomic; disjoint per (half, p)) ----
    {
        float* pw1 = Pout + ((size_t)half*NP + p)*32768;
        float* pw2 = pw1 + 16384;
        #pragma unroll
        for (int nti=0;nti<4;nti++)
            #pragma unroll
            for (int r=0;r<4;r++)
                pw1[(s*16 + q*4 + r)*256 + (ch*4+nti)*16 + ln] = dw1[nti][r];
        #pragma unroll
        for (int ot=0;ot<4;ot++)
            #pragma unroll
            for (int r=0;r<4;r++)
                pw2[(w*16 + q*4 + r)*64 + ot*16 + ln] = dw2[ot][r];
    }
}

// Final masters = M0 - partialA - partialB, folded here; emits the pre-swizzled
// bf16 B-fragment layouts k_apply consumes. (W2tp dropped: only k_apply consumes.)
__global__ __launch_bounds__(256) void k_castW(const float* __restrict__ M0,
                                               const float* __restrict__ P1,
                                               short* __restrict__ W1p,
                                               short* __restrict__ W2p){
    int g = blockIdx.x*256 + threadIdx.x;
    int lane = g & 63;
    int slot = (g >> 6) & 63;
    int p = g / (64*64);
    int q = lane >> 4, ln = lane & 15;
    const float* m1 = M0 + (size_t)p*16384;
    const float* m2 = M0 + (size_t)(NP+p)*16384;
    const float* pa = P1 + (size_t)p*32768;
    const float* pb = P1 + (size_t)(NP+p)*32768;
    if (slot < 32){                              // W1p: B = W1 (64x256)
        int nt = slot >> 1, kk = slot & 1;
        short* dst = W1p + (((size_t)p*32 + slot)*64 + lane)*8;
        #pragma unroll
        for (int j=0;j<8;j++){
            int idx = (kk*32 + q*8 + j)*HID + nt*16 + ln;
            dst[j] = f2b(m1[idx] - pa[idx] - pb[idx]);
        }
    } else {                                     // W2p: B = W2 (256x64)
        int s2 = slot - 32;
        int nt = s2 >> 3, kk = s2 & 7;
        short* dst = W2p + (((size_t)p*32 + s2)*64 + lane)*8;
        #pragma unroll
        for (int j=0;j<8;j++){
            int idx = (kk*32 + q*8 + j)*DD + nt*16 + ln;
            dst[j] = f2b(m2[idx] - pa[16384+idx] - pb[16384+idx]);
        }
    }
}

// out = gelu(q @ W1_final) @ W2_final -> (B, N, H*D) f32.
// Out-tile staged in LDS (reusing hl) -> full-128B-line float4 stores
// (no write-allocate refetch, 4 stores/thread instead of 16).
__global__ __launch_bounds__(256) void k_apply(const float* __restrict__ qin,
                                               const short* __restrict__ W1p,
                                               const short* __restrict__ W2p,
                                               float* __restrict__ out){
    int p = blockIdx.x >> 5, mt = blockIdx.x & 31;
    int tid = threadIdx.x;
    int w = tid >> 6, lane = tid & 63, q = lane >> 4, ln = lane & 15;
    int m0 = mt*64;
    int b = p >> 4, h = p & 15;
    __shared__ __attribute__((aligned(16))) short hl[64*264];
    float* ol = (float*)hl;                      // reused as [64][68] f32
    const float* xbase = qin + ((size_t)p*NTOK + m0 + w*16 + ln)*DD;
    frag8 af[2];
    #pragma unroll
    for (int kk=0;kk<2;kk++){
        const float* xr = xbase + kk*32 + q*8;
        float4 u0 = *(const float4*)xr;
        float4 u1 = *(const float4*)(xr+4);
        frag8 a;
        a[0]=f2b(u0.x); a[1]=f2b(u0.y); a[2]=f2b(u0.z); a[3]=f2b(u0.w);
        a[4]=f2b(u1.x); a[5]=f2b(u1.y); a[6]=f2b(u1.z); a[7]=f2b(u1.w);
        af[kk]=a;
    }
    const short* w1b = W1p + ((size_t)p*32*64 + lane)*8;
    #pragma unroll
    for (int nt=0;nt<16;nt++){
        frag4f zc = {0.f,0.f,0.f,0.f};
        #pragma unroll
        for (int kk=0;kk<2;kk++){
            frag8 bfr = *(const frag8*)(w1b + (size_t)(nt*2+kk)*64*8);
            zc = MFMA(af[kk], bfr, zc);
        }
        #pragma unroll
        for (int r=0;r<4;r++){
            int row = w*16 + q*4 + r;
            hl[row*264 + SW(row, nt*16 + ln)] = f2b(gelu_f(zc[r]));
        }
    }
    __syncthreads();
    frag8 hfr[8];
    #pragma unroll
    for (int kk=0;kk<8;kk++)
        hfr[kk] = *(const frag8*)(&hl[(w*16+ln)*264 + SW(w*16+ln, kk*32 + q*8)]);
    __syncthreads();   // all hl reads done before ol overwrite
    const short* w2b = W2p + ((size_t)p*32*64 + lane)*8;
    frag4f oc4[4];
    #pragma unroll
    for (int nt=0;nt<4;nt++){
        frag4f oc = {0.f,0.f,0.f,0.f};
        #pragma unroll
        for (int kk=0;kk<8;kk++){
            frag8 bfr = *(const frag8*)(w2b + (size_t)(nt*8+kk)*64*8);
            oc = MFMA(hfr[kk], bfr, oc);
        }
        oc4[nt] = oc;
    }
    #pragma unroll
    for (int nt=0;nt<4;nt++)
        #pragma unroll
        for (int r=0;r<4;r++)
            ol[(w*16+q*4+r)*68 + nt*16 + ln] = oc4[nt][r];
    __syncthreads();
    // cooperative write: 8 lanes x 16B = one full 128B line per row per instr
    size_t obase = ((size_t)b*NTOK + m0)*(HH*DD) + (size_t)h*DD;
    int c8 = tid & 7;
    #pragma unroll
    for (int pass=0; pass<2; pass++){
        int row = pass*32 + (tid>>3);
        #pragma unroll
        for (int u=0; u<2; u++){
            float4 vv = *(const float4*)&ol[row*68 + (c8 + u*8)*4];
            *(float4*)&out[obase + (size_t)row*(HH*DD) + (c8 + u*8)*4] = vv;
        }
    }
}

extern "C" void kernel_launch(void* const* d_in, const int* in_sizes, int n_in,
                              void* d_out, int out_size, void* d_ws, size_t ws_size,
                              hipStream_t stream) {
    (void)in_sizes; (void)n_in; (void)out_size; (void)ws_size;
    const float* q  = (const float*)d_in[0];
    const float* k  = (const float*)d_in[1];
    const float* v  = (const float*)d_in[2];
    const float* W1 = (const float*)d_in[3];
    const float* W2 = (const float*)d_in[4];
    float* out = (float*)d_out;

    // ws: P0 partials; later overlapped by W1p/W2p
    // (P0 is dead after the t=3 read, before k_castW writes).
    float* P0  = (float*)d_ws;                        // NP*2*32768 f32
    short* W1p = (short*)d_ws;                        // 2x NP*16384 bf16 (overlap P0)
    short* W2p = W1p + (size_t)NP*16384;

    // d_out scratch: M0, M1 masters + P1 partials.
    // All dead before k_apply overwrites d_out with the real output.
    float* M0 = (float*)d_out;                        // NP*32768 f32 (W1|W2)
    float* M1 = M0 + (size_t)NP*32768;
    float* P1 = M1 + (size_t)NP*32768;                // NP*2*32768 f32

    // iter t uses masters_{t-1} = Mold - partials_{t-1}; writes masters_{t-1} to Mnew
    // and its own dW_t partial to Pout.
    //                           kin vin  MoW1  MoW2                      Pin  Mnew Pout hIdx fold t
    k_step<<<256,1024,0,stream>>>(k, v,  W1,   W2,                        P0,  M1,  P0,  1,   0,  0);
    k_step<<<256,1024,0,stream>>>(k, v,  M1,   M1+(size_t)NP*16384,       P0,  M0,  P1,  0,   1,  1);
    k_step<<<256,1024,0,stream>>>(k, v,  M0,   M0+(size_t)NP*16384,       P1,  M1,  P0,  0,   1,  2);
    k_step<<<256,1024,0,stream>>>(k, v,  M1,   M1+(size_t)NP*16384,       P0,  M0,  P1,  0,   1,  3);
    // masters_3 = M0 - P1, folded inside k_castW
    k_castW<<<NP*16, 256, 0, stream>>>(M0, P1, W1p, W2p);
    k_apply<<<NP*32, 256, 0, stream>>>(q, W1p, W2p, out);
}

// Round 5
// 504.573 us; speedup vs baseline: 1.1295x; 1.1295x over previous
//
#include <hip/hip_runtime.h>
#include <hip/hip_bf16.h>

typedef __hip_bfloat16 bf16;
typedef __attribute__((ext_vector_type(8))) short frag8;   // 8 bf16 = 4 VGPR
typedef __attribute__((ext_vector_type(4))) float frag4f;  // MFMA C/D
typedef __attribute__((ext_vector_type(4))) short short4v; // 8B packed store

#define BB 8
#define HH 16
#define NTOK 2048
#define DD 64
#define HID 256
#define NIT 4
#define CH 512
#define NP 128
#define INV_CD 3.0517578125e-05f  // 1/(CH*DD)

#define MFMA(a,b,c) __builtin_amdgcn_mfma_f32_16x16x32_bf16((a),(b),(c),0,0,0)

// XOR swizzle: spreads 8-row-strided column reads across disjoint 8-bank
// windows (row stride 528B === 0 mod 128B otherwise -> 8-way conflict).
// Keeps frag8 16B alignment (toggles col bits 4-5 only).
#define SW(row,col) ((col) ^ ((((row)>>3)&3)<<4))

__device__ __forceinline__ short f2b(float f){
    union { __hip_bfloat16 b; short s; } u;
    u.b = __float2bfloat16(f);
    return u.s;
}

// Fast tanh via hardware exp: t = 1 - 2/(e^{2u}+1). Stable at +/-inf.
__device__ __forceinline__ float tanh_fast(float u){
    float e = __expf(2.0f*u);
    return 1.0f - 2.0f/(e+1.0f);
}

__device__ __forceinline__ float gelu_f(float x){
    const float c0 = 0.7978845608028654f, c1 = 0.044715f;
    float u = c0*(x + c1*x*x*x);
    float t = tanh_fast(u);
    return 0.5f*x*(1.0f+t);
}

// Fused gelu value + grad: ONE tanh shared.
__device__ __forceinline__ void gelu_both(float x, float* hv, float* gp){
    const float c0 = 0.7978845608028654f, c1 = 0.044715f;
    float x2 = x*x;
    float u = c0*(x + c1*x2*x);
    float t = tanh_fast(u);
    *hv = 0.5f*x*(1.0f+t);
    *gp = 0.5f*(1.0f+t) + 0.5f*x*(1.0f-t*t)*c0*(1.0f+3.0f*c1*x2);
}

// One fused inner-loop iteration. Block = (pair p, token-half). 1024 threads,
// 16 waves (4 row-strips x 4 column-groups). hl/W2c XOR-swizzled (conflict-free
// strided column reads in P3/P4). __launch_bounds__(1024,4): LDS caps us at
// 1 block/CU = 4 waves/EU anyway; declaring it pins the VGPR budget to 128 and
// prevents the 64-VGPR spilling schedule (round-4 regression: scratch traffic
// +110MB/dispatch).
__global__ __launch_bounds__(1024, 4) void k_step(
    const float* __restrict__ kin, const float* __restrict__ vin,
    const float* __restrict__ MoW1, const float* __restrict__ MoW2,
    const float* __restrict__ Pin,  float* __restrict__ Mnew,
    float* __restrict__ Pout, int hIdx, int fold, int t)
{
    int p = blockIdx.x >> 1, half = blockIdx.x & 1;
    int tid = threadIdx.x;
    int w = tid >> 6, lane = tid & 63, q = lane >> 4, ln = lane & 15;
    int s = w >> 2, ch = w & 3;   // row-strip (16 rows), column quarter

    // 156 KB total -> 1 block/CU
    __shared__ __attribute__((aligned(16))) short W1c[256*72];   // W1^T [e'][d]
    __shared__ __attribute__((aligned(16))) short W2c[64*264];   // W2^T [o][e'] (swz)
    __shared__ __attribute__((aligned(16))) short hl [64*264];   // h  [m][e'] (swz)
    __shared__ __attribute__((aligned(16))) short el [64*72];    // e  [m][o]
    __shared__ __attribute__((aligned(16))) short eTl[64*72];    // e^T [o][m]
    __shared__ __attribute__((aligned(16))) short dzTl[256*72];  // dz^T [e'][m]

    // ---- cast masters -> LDS bf16 (+ fold partials, + materialize Mnew) ----
    {
        int widx = hIdx ? (p & 15) : p;
        const float* w1o = MoW1 + (size_t)widx*16384;
        const float* w2o = MoW2 + (size_t)widx*16384;
        const float* pa = Pin + (size_t)p*32768;
        const float* pb = Pin + (size_t)(NP+p)*32768;
        float* mn1 = Mnew + (size_t)p*16384;
        float* mn2 = Mnew + (size_t)(NP+p)*16384;
        #pragma unroll 4
        for (int i=0;i<16;i++){
            int src = i*1024 + tid;
            float a = w1o[src];
            float b = w2o[src];
            if (fold){
                a -= pa[src] + pb[src];
                b -= pa[16384+src] + pb[16384+src];
            }
            mn1[src] = a;
            mn2[src] = b;
            W1c[(src & 255)*72  + (src >> 8)] = f2b(a);              // [e'][d]
            W2c[(src & 63)*264  + SW(src & 63, src >> 6)] = f2b(b);  // [o][e'] swz
        }
    }
    __syncthreads();

    frag4f dw1[4], dw2[4];
    #pragma unroll
    for (int i=0;i<4;i++){ frag4f zz = {0.f,0.f,0.f,0.f}; dw1[i]=zz; dw2[i]=zz; }

    size_t rowbase = (size_t)p*NTOK + (size_t)t*CH + (size_t)half*256;

    #pragma unroll 1
    for (int mt=0; mt<4; ++mt){
        int m0 = mt*64;

        // ---------- P1: z = x@W1 ; h=gelu(z)->hl ; zacc := gelu'(z) ----------
        frag8 af[2];
        {
            const float* xb = kin + (rowbase + m0 + s*16 + ln)*DD;
            #pragma unroll
            for (int kk=0;kk<2;kk++){
                const float* xr = xb + kk*32 + q*8;
                float4 u0 = *(const float4*)xr;
                float4 u1 = *(const float4*)(xr+4);
                frag8 a;
                a[0]=f2b(u0.x); a[1]=f2b(u0.y); a[2]=f2b(u0.z); a[3]=f2b(u0.w);
                a[4]=f2b(u1.x); a[5]=f2b(u1.y); a[6]=f2b(u1.z); a[7]=f2b(u1.w);
                af[kk]=a;
            }
        }
        frag4f zacc[4];
        #pragma unroll
        for (int nti=0;nti<4;nti++){
            frag4f zc = {0.f,0.f,0.f,0.f};
            #pragma unroll
            for (int kk=0;kk<2;kk++){
                frag8 b = *(const frag8*)&W1c[((ch*4+nti)*16+ln)*72 + kk*32 + q*8];
                zc = MFMA(af[kk], b, zc);
            }
            zacc[nti] = zc;
        }
        #pragma unroll
        for (int nti=0;nti<4;nti++)
            #pragma unroll
            for (int r=0;r<4;r++){
                float hv, gp;
                gelu_both(zacc[nti][r], &hv, &gp);
                int row = s*16+q*4+r;
                hl[row*264 + SW(row, (ch*4+nti)*16 + ln)] = f2b(hv);
                zacc[nti][r] = gp;
            }
        __syncthreads();

        // ---------- P2: out = h@W2 ; e=(out-y)*s -> el,eTl ----------
        {
            frag8 hfr[8];
            #pragma unroll
            for (int kk=0;kk<8;kk++)
                hfr[kk] = *(const frag8*)&hl[(s*16+ln)*264 + SW(s*16+ln, kk*32 + q*8)];
            frag4f oc = {0.f,0.f,0.f,0.f};
            #pragma unroll
            for (int kk=0;kk<8;kk++){
                frag8 b = *(const frag8*)&W2c[(ch*16+ln)*264 + SW(ch*16+ln, kk*32 + q*8)];
                oc = MFMA(hfr[kk], b, oc);
            }
            short4v ep;
            #pragma unroll
            for (int r=0;r<4;r++){
                float y = vin[(rowbase + m0 + s*16 + q*4 + r)*DD + ch*16 + ln];
                float e = (oc[r]-y)*INV_CD;
                el[(s*16+q*4+r)*72 + ch*16 + ln] = f2b(e);
                ep[r] = f2b(e);
            }
            *(short4v*)&eTl[(ch*16+ln)*72 + s*16 + q*4] = ep;
        }
        __syncthreads();

        // ---------- P3: dz = (e@W2^T) * gelu'(z) -> dzTl ----------
        {
            frag8 efr[2];
            #pragma unroll
            for (int kk=0;kk<2;kk++)
                efr[kk] = *(const frag8*)&el[(s*16+ln)*72 + kk*32 + q*8];
            #pragma unroll
            for (int nti=0;nti<4;nti++){
                int nt = ch*4 + nti;
                frag4f dc = {0.f,0.f,0.f,0.f};
                #pragma unroll
                for (int kk=0;kk<2;kk++){
                    frag8 b;
                    #pragma unroll
                    for (int j=0;j<8;j++){
                        int row = kk*32+q*8+j;
                        b[j] = W2c[row*264 + SW(row, nt*16 + ln)];  // conflict-free
                    }
                    dc = MFMA(efr[kk], b, dc);
                }
                short4v dp;
                #pragma unroll
                for (int r=0;r<4;r++)
                    dp[r] = f2b(dc[r]*zacc[nti][r]);
                *(short4v*)&dzTl[(nt*16+ln)*72 + s*16 + q*4] = dp;
            }
        }
        __syncthreads();

        // ---------- P4: dW1 += x^T@dz ; dW2 += h^T@e ----------
        {
            #pragma unroll
            for (int kk2=0;kk2<2;kk2++){
                frag8 a;
                #pragma unroll
                for (int j=0;j<8;j++)
                    a[j] = f2b(kin[(rowbase + m0 + kk2*32 + q*8 + j)*DD + s*16 + ln]);
                #pragma unroll
                for (int nti=0;nti<4;nti++){
                    frag8 b = *(const frag8*)&dzTl[((ch*4+nti)*16+ln)*72 + kk2*32 + q*8];
                    dw1[nti] = MFMA(a, b, dw1[nti]);
                }
            }
            #pragma unroll
            for (int kk2=0;kk2<2;kk2++){
                frag8 a;
                #pragma unroll
                for (int j=0;j<8;j++){
                    int row = kk2*32+q*8+j;
                    a[j] = hl[row*264 + SW(row, w*16 + ln)];        // conflict-free
                }
                #pragma unroll
                for (int ot=0;ot<4;ot++){
                    frag8 b = *(const frag8*)&eTl[(ot*16+ln)*72 + kk2*32 + q*8];
                    dw2[ot] = MFMA(a, b, dw2[ot]);
                }
            }
        }
        __syncthreads();
    }

    // ---- write partial dW (non-atomic; disjoint per (half, p)) ----
    {
        float* pw1 = Pout + ((size_t)half*NP + p)*32768;
        float* pw2 = pw1 + 16384;
        #pragma unroll
        for (int nti=0;nti<4;nti++)
            #pragma unroll
            for (int r=0;r<4;r++)
                pw1[(s*16 + q*4 + r)*256 + (ch*4+nti)*16 + ln] = dw1[nti][r];
        #pragma unroll
        for (int ot=0;ot<4;ot++)
            #pragma unroll
            for (int r=0;r<4;r++)
                pw2[(w*16 + q*4 + r)*64 + ot*16 + ln] = dw2[ot][r];
    }
}

// Final masters = M0 - partialA - partialB, folded here; emits the pre-swizzled
// bf16 B-fragment layouts k_apply consumes.
__global__ __launch_bounds__(256) void k_castW(const float* __restrict__ M0,
                                               const float* __restrict__ P1,
                                               short* __restrict__ W1p,
                                               short* __restrict__ W2p){
    int g = blockIdx.x*256 + threadIdx.x;
    int lane = g & 63;
    int slot = (g >> 6) & 63;
    int p = g / (64*64);
    int q = lane >> 4, ln = lane & 15;
    const float* m1 = M0 + (size_t)p*16384;
    const float* m2 = M0 + (size_t)(NP+p)*16384;
    const float* pa = P1 + (size_t)p*32768;
    const float* pb = P1 + (size_t)(NP+p)*32768;
    if (slot < 32){                              // W1p: B = W1 (64x256)
        int nt = slot >> 1, kk = slot & 1;
        short* dst = W1p + (((size_t)p*32 + slot)*64 + lane)*8;
        #pragma unroll
        for (int j=0;j<8;j++){
            int idx = (kk*32 + q*8 + j)*HID + nt*16 + ln;
            dst[j] = f2b(m1[idx] - pa[idx] - pb[idx]);
        }
    } else {                                     // W2p: B = W2 (256x64)
        int s2 = slot - 32;
        int nt = s2 >> 3, kk = s2 & 7;
        short* dst = W2p + (((size_t)p*32 + s2)*64 + lane)*8;
        #pragma unroll
        for (int j=0;j<8;j++){
            int idx = (kk*32 + q*8 + j)*DD + nt*16 + ln;
            dst[j] = f2b(m2[idx] - pa[16384+idx] - pb[16384+idx]);
        }
    }
}

// out = gelu(q @ W1_final) @ W2_final -> (B, N, H*D) f32.
// Out-tile staged in LDS (reusing hl) -> full-128B-line float4 stores
// (no write-allocate refetch, 4 stores/thread instead of 16).
__global__ __launch_bounds__(256) void k_apply(const float* __restrict__ qin,
                                               const short* __restrict__ W1p,
                                               const short* __restrict__ W2p,
                                               float* __restrict__ out){
    int p = blockIdx.x >> 5, mt = blockIdx.x & 31;
    int tid = threadIdx.x;
    int w = tid >> 6, lane = tid & 63, q = lane >> 4, ln = lane & 15;
    int m0 = mt*64;
    int b = p >> 4, h = p & 15;
    __shared__ __attribute__((aligned(16))) short hl[64*264];
    float* ol = (float*)hl;                      // reused as [64][68] f32
    const float* xbase = qin + ((size_t)p*NTOK + m0 + w*16 + ln)*DD;
    frag8 af[2];
    #pragma unroll
    for (int kk=0;kk<2;kk++){
        const float* xr = xbase + kk*32 + q*8;
        float4 u0 = *(const float4*)xr;
        float4 u1 = *(const float4*)(xr+4);
        frag8 a;
        a[0]=f2b(u0.x); a[1]=f2b(u0.y); a[2]=f2b(u0.z); a[3]=f2b(u0.w);
        a[4]=f2b(u1.x); a[5]=f2b(u1.y); a[6]=f2b(u1.z); a[7]=f2b(u1.w);
        af[kk]=a;
    }
    const short* w1b = W1p + ((size_t)p*32*64 + lane)*8;
    #pragma unroll
    for (int nt=0;nt<16;nt++){
        frag4f zc = {0.f,0.f,0.f,0.f};
        #pragma unroll
        for (int kk=0;kk<2;kk++){
            frag8 bfr = *(const frag8*)(w1b + (size_t)(nt*2+kk)*64*8);
            zc = MFMA(af[kk], bfr, zc);
        }
        #pragma unroll
        for (int r=0;r<4;r++){
            int row = w*16 + q*4 + r;
            hl[row*264 + SW(row, nt*16 + ln)] = f2b(gelu_f(zc[r]));
        }
    }
    __syncthreads();
    frag8 hfr[8];
    #pragma unroll
    for (int kk=0;kk<8;kk++)
        hfr[kk] = *(const frag8*)(&hl[(w*16+ln)*264 + SW(w*16+ln, kk*32 + q*8)]);
    __syncthreads();   // all hl reads done before ol overwrite
    const short* w2b = W2p + ((size_t)p*32*64 + lane)*8;
    frag4f oc4[4];
    #pragma unroll
    for (int nt=0;nt<4;nt++){
        frag4f oc = {0.f,0.f,0.f,0.f};
        #pragma unroll
        for (int kk=0;kk<8;kk++){
            frag8 bfr = *(const frag8*)(w2b + (size_t)(nt*8+kk)*64*8);
            oc = MFMA(hfr[kk], bfr, oc);
        }
        oc4[nt] = oc;
    }
    #pragma unroll
    for (int nt=0;nt<4;nt++)
        #pragma unroll
        for (int r=0;r<4;r++)
            ol[(w*16+q*4+r)*68 + nt*16 + ln] = oc4[nt][r];
    __syncthreads();
    // cooperative write: 8 lanes x 16B = one full 128B line per row per instr
    size_t obase = ((size_t)b*NTOK + m0)*(HH*DD) + (size_t)h*DD;
    int c8 = tid & 7;
    #pragma unroll
    for (int pass=0; pass<2; pass++){
        int row = pass*32 + (tid>>3);
        #pragma unroll
        for (int u=0; u<2; u++){
            float4 vv = *(const float4*)&ol[row*68 + (c8 + u*8)*4];
            *(float4*)&out[obase + (size_t)row*(HH*DD) + (c8 + u*8)*4] = vv;
        }
    }
}

extern "C" void kernel_launch(void* const* d_in, const int* in_sizes, int n_in,
                              void* d_out, int out_size, void* d_ws, size_t ws_size,
                              hipStream_t stream) {
    (void)in_sizes; (void)n_in; (void)out_size; (void)ws_size;
    const float* q  = (const float*)d_in[0];
    const float* k  = (const float*)d_in[1];
    const float* v  = (const float*)d_in[2];
    const float* W1 = (const float*)d_in[3];
    const float* W2 = (const float*)d_in[4];
    float* out = (float*)d_out;

    // ws: P0 partials; later overlapped by W1p/W2p
    // (P0 is dead after the t=3 read, before k_castW writes).
    float* P0  = (float*)d_ws;                        // NP*2*32768 f32
    short* W1p = (short*)d_ws;                        // 2x NP*16384 bf16 (overlap P0)
    short* W2p = W1p + (size_t)NP*16384;

    // d_out scratch: M0, M1 masters + P1 partials.
    // All dead before k_apply overwrites d_out with the real output.
    float* M0 = (float*)d_out;                        // NP*32768 f32 (W1|W2)
    float* M1 = M0 + (size_t)NP*32768;
    float* P1 = M1 + (size_t)NP*32768;                // NP*2*32768 f32

    // iter t uses masters_{t-1} = Mold - partials_{t-1}; writes masters_{t-1} to Mnew
    // and its own dW_t partial to Pout.
    //                           kin vin  MoW1  MoW2                      Pin  Mnew Pout hIdx fold t
    k_step<<<256,1024,0,stream>>>(k, v,  W1,   W2,                        P0,  M1,  P0,  1,   0,  0);
    k_step<<<256,1024,0,stream>>>(k, v,  M1,   M1+(size_t)NP*16384,       P0,  M0,  P1,  0,   1,  1);
    k_step<<<256,1024,0,stream>>>(k, v,  M0,   M0+(size_t)NP*16384,       P1,  M1,  P0,  0,   1,  2);
    k_step<<<256,1024,0,stream>>>(k, v,  M1,   M1+(size_t)NP*16384,       P0,  M0,  P1,  0,   1,  3);
    // masters_3 = M0 - P1, folded inside k_castW
    k_castW<<<NP*16, 256, 0, stream>>>(M0, P1, W1p, W2p);
    k_apply<<<NP*32, 256, 0, stream>>>(q, W1p, W2p, out);
}

// Round 6
// 500.504 us; speedup vs baseline: 1.1387x; 1.0081x over previous
//
#include <hip/hip_runtime.h>
#include <hip/hip_bf16.h>

typedef __hip_bfloat16 bf16;
typedef __attribute__((ext_vector_type(8))) short frag8;   // 8 bf16 = 4 VGPR
typedef __attribute__((ext_vector_type(4))) float frag4f;  // MFMA C/D
typedef __attribute__((ext_vector_type(4))) short short4v; // 8B packed store

#define BB 8
#define HH 16
#define NTOK 2048
#define DD 64
#define HID 256
#define NIT 4
#define CH 512
#define NP 128
#define INV_CD 3.0517578125e-05f  // 1/(CH*DD)

#define MFMA(a,b,c) __builtin_amdgcn_mfma_f32_16x16x32_bf16((a),(b),(c),0,0,0)

// XOR swizzle (k_step only): spreads 8-row-strided column reads across disjoint
// 8-bank windows (row stride 528B === 0 mod 128B otherwise -> 8-way conflict).
#define SW(row,col) ((col) ^ ((((row)>>3)&3)<<4))

__device__ __forceinline__ short f2b(float f){
    union { __hip_bfloat16 b; short s; } u;
    u.b = __float2bfloat16(f);
    return u.s;
}

// Fast tanh via hardware exp: t = 1 - 2/(e^{2u}+1). Stable at +/-inf.
__device__ __forceinline__ float tanh_fast(float u){
    float e = __expf(2.0f*u);
    return 1.0f - 2.0f/(e+1.0f);
}

__device__ __forceinline__ float gelu_f(float x){
    const float c0 = 0.7978845608028654f, c1 = 0.044715f;
    float u = c0*(x + c1*x*x*x);
    float t = tanh_fast(u);
    return 0.5f*x*(1.0f+t);
}

// Fused gelu value + grad: ONE tanh shared.
__device__ __forceinline__ void gelu_both(float x, float* hv, float* gp){
    const float c0 = 0.7978845608028654f, c1 = 0.044715f;
    float x2 = x*x;
    float u = c0*(x + c1*x2*x);
    float t = tanh_fast(u);
    *hv = 0.5f*x*(1.0f+t);
    *gp = 0.5f*(1.0f+t) + 0.5f*x*(1.0f-t*t)*c0*(1.0f+3.0f*c1*x2);
}

// One fused inner-loop iteration. Block = (pair p, token-half). 1024 threads,
// 16 waves (4 row-strips x 4 column-groups). hl/W2c XOR-swizzled (conflict-free
// strided column reads in P3/P4). __launch_bounds__(1024,4) pins the VGPR
// budget to 128 (prevents the round-4 64-VGPR spilling schedule).
__global__ __launch_bounds__(1024, 4) void k_step(
    const float* __restrict__ kin, const float* __restrict__ vin,
    const float* __restrict__ MoW1, const float* __restrict__ MoW2,
    const float* __restrict__ Pin,  float* __restrict__ Mnew,
    float* __restrict__ Pout, int hIdx, int fold, int t)
{
    int p = blockIdx.x >> 1, half = blockIdx.x & 1;
    int tid = threadIdx.x;
    int w = tid >> 6, lane = tid & 63, q = lane >> 4, ln = lane & 15;
    int s = w >> 2, ch = w & 3;   // row-strip (16 rows), column quarter

    // 156 KB total -> 1 block/CU
    __shared__ __attribute__((aligned(16))) short W1c[256*72];   // W1^T [e'][d]
    __shared__ __attribute__((aligned(16))) short W2c[64*264];   // W2^T [o][e'] (swz)
    __shared__ __attribute__((aligned(16))) short hl [64*264];   // h  [m][e'] (swz)
    __shared__ __attribute__((aligned(16))) short el [64*72];    // e  [m][o]
    __shared__ __attribute__((aligned(16))) short eTl[64*72];    // e^T [o][m]
    __shared__ __attribute__((aligned(16))) short dzTl[256*72];  // dz^T [e'][m]

    // ---- cast masters -> LDS bf16 (+ fold partials, + materialize Mnew) ----
    {
        int widx = hIdx ? (p & 15) : p;
        const float* w1o = MoW1 + (size_t)widx*16384;
        const float* w2o = MoW2 + (size_t)widx*16384;
        const float* pa = Pin + (size_t)p*32768;
        const float* pb = Pin + (size_t)(NP+p)*32768;
        float* mn1 = Mnew + (size_t)p*16384;
        float* mn2 = Mnew + (size_t)(NP+p)*16384;
        #pragma unroll 4
        for (int i=0;i<16;i++){
            int src = i*1024 + tid;
            float a = w1o[src];
            float b = w2o[src];
            if (fold){
                a -= pa[src] + pb[src];
                b -= pa[16384+src] + pb[16384+src];
            }
            if (half == 0){            // dedup: both halves compute identical a,b
                mn1[src] = a;
                mn2[src] = b;
            }
            W1c[(src & 255)*72  + (src >> 8)] = f2b(a);              // [e'][d]
            W2c[(src & 63)*264  + SW(src & 63, src >> 6)] = f2b(b);  // [o][e'] swz
        }
    }
    __syncthreads();

    frag4f dw1[4], dw2[4];
    #pragma unroll
    for (int i=0;i<4;i++){ frag4f zz = {0.f,0.f,0.f,0.f}; dw1[i]=zz; dw2[i]=zz; }

    size_t rowbase = (size_t)p*NTOK + (size_t)t*CH + (size_t)half*256;

    #pragma unroll 1
    for (int mt=0; mt<4; ++mt){
        int m0 = mt*64;

        // ---------- P1: z = x@W1 ; h=gelu(z)->hl ; zacc := gelu'(z) ----------
        frag8 af[2];
        {
            const float* xb = kin + (rowbase + m0 + s*16 + ln)*DD;
            #pragma unroll
            for (int kk=0;kk<2;kk++){
                const float* xr = xb + kk*32 + q*8;
                float4 u0 = *(const float4*)xr;
                float4 u1 = *(const float4*)(xr+4);
                frag8 a;
                a[0]=f2b(u0.x); a[1]=f2b(u0.y); a[2]=f2b(u0.z); a[3]=f2b(u0.w);
                a[4]=f2b(u1.x); a[5]=f2b(u1.y); a[6]=f2b(u1.z); a[7]=f2b(u1.w);
                af[kk]=a;
            }
        }
        frag4f zacc[4];
        #pragma unroll
        for (int nti=0;nti<4;nti++){
            frag4f zc = {0.f,0.f,0.f,0.f};
            #pragma unroll
            for (int kk=0;kk<2;kk++){
                frag8 b = *(const frag8*)&W1c[((ch*4+nti)*16+ln)*72 + kk*32 + q*8];
                zc = MFMA(af[kk], b, zc);
            }
            zacc[nti] = zc;
        }
        #pragma unroll
        for (int nti=0;nti<4;nti++)
            #pragma unroll
            for (int r=0;r<4;r++){
                float hv, gp;
                gelu_both(zacc[nti][r], &hv, &gp);
                int row = s*16+q*4+r;
                hl[row*264 + SW(row, (ch*4+nti)*16 + ln)] = f2b(hv);
                zacc[nti][r] = gp;
            }
        __syncthreads();

        // ---------- P2: out = h@W2 ; e=(out-y)*s -> el,eTl ----------
        {
            frag8 hfr[8];
            #pragma unroll
            for (int kk=0;kk<8;kk++)
                hfr[kk] = *(const frag8*)&hl[(s*16+ln)*264 + SW(s*16+ln, kk*32 + q*8)];
            frag4f oc = {0.f,0.f,0.f,0.f};
            #pragma unroll
            for (int kk=0;kk<8;kk++){
                frag8 b = *(const frag8*)&W2c[(ch*16+ln)*264 + SW(ch*16+ln, kk*32 + q*8)];
                oc = MFMA(hfr[kk], b, oc);
            }
            short4v ep;
            #pragma unroll
            for (int r=0;r<4;r++){
                float y = vin[(rowbase + m0 + s*16 + q*4 + r)*DD + ch*16 + ln];
                float e = (oc[r]-y)*INV_CD;
                el[(s*16+q*4+r)*72 + ch*16 + ln] = f2b(e);
                ep[r] = f2b(e);
            }
            *(short4v*)&eTl[(ch*16+ln)*72 + s*16 + q*4] = ep;
        }
        __syncthreads();

        // ---------- P3: dz = (e@W2^T) * gelu'(z) -> dzTl ----------
        {
            frag8 efr[2];
            #pragma unroll
            for (int kk=0;kk<2;kk++)
                efr[kk] = *(const frag8*)&el[(s*16+ln)*72 + kk*32 + q*8];
            #pragma unroll
            for (int nti=0;nti<4;nti++){
                int nt = ch*4 + nti;
                frag4f dc = {0.f,0.f,0.f,0.f};
                #pragma unroll
                for (int kk=0;kk<2;kk++){
                    frag8 b;
                    #pragma unroll
                    for (int j=0;j<8;j++){
                        int row = kk*32+q*8+j;
                        b[j] = W2c[row*264 + SW(row, nt*16 + ln)];  // conflict-free
                    }
                    dc = MFMA(efr[kk], b, dc);
                }
                short4v dp;
                #pragma unroll
                for (int r=0;r<4;r++)
                    dp[r] = f2b(dc[r]*zacc[nti][r]);
                *(short4v*)&dzTl[(nt*16+ln)*72 + s*16 + q*4] = dp;
            }
        }
        __syncthreads();

        // ---------- P4: dW1 += x^T@dz ; dW2 += h^T@e ----------
        {
            #pragma unroll
            for (int kk2=0;kk2<2;kk2++){
                frag8 a;
                #pragma unroll
                for (int j=0;j<8;j++)
                    a[j] = f2b(kin[(rowbase + m0 + kk2*32 + q*8 + j)*DD + s*16 + ln]);
                #pragma unroll
                for (int nti=0;nti<4;nti++){
                    frag8 b = *(const frag8*)&dzTl[((ch*4+nti)*16+ln)*72 + kk2*32 + q*8];
                    dw1[nti] = MFMA(a, b, dw1[nti]);
                }
            }
            #pragma unroll
            for (int kk2=0;kk2<2;kk2++){
                frag8 a;
                #pragma unroll
                for (int j=0;j<8;j++){
                    int row = kk2*32+q*8+j;
                    a[j] = hl[row*264 + SW(row, w*16 + ln)];        // conflict-free
                }
                #pragma unroll
                for (int ot=0;ot<4;ot++){
                    frag8 b = *(const frag8*)&eTl[(ot*16+ln)*72 + kk2*32 + q*8];
                    dw2[ot] = MFMA(a, b, dw2[ot]);
                }
            }
        }
        __syncthreads();
    }

    // ---- write partial dW (non-atomic; disjoint per (half, p)) ----
    {
        float* pw1 = Pout + ((size_t)half*NP + p)*32768;
        float* pw2 = pw1 + 16384;
        #pragma unroll
        for (int nti=0;nti<4;nti++)
            #pragma unroll
            for (int r=0;r<4;r++)
                pw1[(s*16 + q*4 + r)*256 + (ch*4+nti)*16 + ln] = dw1[nti][r];
        #pragma unroll
        for (int ot=0;ot<4;ot++)
            #pragma unroll
            for (int r=0;r<4;r++)
                pw2[(w*16 + q*4 + r)*64 + ot*16 + ln] = dw2[ot][r];
    }
}

// Final masters = M0 - partialA - partialB. Coalesced rewrite: one block per
// (p, W1|W2); float4-coalesced fold into padded LDS f32 tile, then each thread
// emits 2 pre-swizzled bf16 fragment rows as single 16B stores.
__global__ __launch_bounds__(1024) void k_castW(const float* __restrict__ M0,
                                                const float* __restrict__ P1,
                                                short* __restrict__ W1p,
                                                short* __restrict__ W2p){
    int p = blockIdx.x >> 1, which = blockIdx.x & 1;
    int tid = threadIdx.x;
    __shared__ float F[256*65];    // W1 view: [64][257]; W2 view: [256][65]
    const float* m  = M0 + ((size_t)(which ? NP+p : p))*16384;
    const float* pa = P1 + (size_t)p*32768      + (size_t)which*16384;
    const float* pb = P1 + (size_t)(NP+p)*32768 + (size_t)which*16384;

    // coalesced fold: 4 float4 per thread
    #pragma unroll
    for (int i=0;i<4;i++){
        int idx4 = i*4096 + tid*4;
        float4 mv = *(const float4*)(m  + idx4);
        float4 av = *(const float4*)(pa + idx4);
        float4 bv = *(const float4*)(pb + idx4);
        float vv[4] = { mv.x-av.x-bv.x, mv.y-av.y-bv.y, mv.z-av.z-bv.z, mv.w-av.w-bv.w };
        if (which == 0){               // W1 [d=64][e'=256], pad 257
            int row = idx4 >> 8, col = idx4 & 255;
            #pragma unroll
            for (int e=0;e<4;e++) F[row*257 + col + e] = vv[e];
        } else {                       // W2 [e'=256][o=64], pad 65
            int row = idx4 >> 6, col = idx4 & 63;
            #pragma unroll
            for (int e=0;e<4;e++) F[row*65 + col + e] = vv[e];
        }
    }
    __syncthreads();

    // emit 2 fragment rows per thread (32 slots x 64 "lanes" = 2048)
    #pragma unroll
    for (int inst=0;inst<2;inst++){
        int fi = inst*1024 + tid;
        int slot = fi >> 6, l = fi & 63;
        int qf = l >> 4, lnf = l & 15;
        frag8 v;
        if (which == 0){               // W1p: elem j = W1[kk*32+qf*8+j][nt*16+lnf]
            int nt = slot >> 1, kk = slot & 1;
            #pragma unroll
            for (int j=0;j<8;j++)
                v[j] = f2b(F[(kk*32 + qf*8 + j)*257 + nt*16 + lnf]);
            *(frag8*)(W1p + (((size_t)p*32 + slot)*64 + l)*8) = v;
        } else {                       // W2p: elem j = W2[kk*32+qf*8+j][nt*16+lnf]
            int nt = slot >> 3, kk = slot & 7;
            #pragma unroll
            for (int j=0;j<8;j++)
                v[j] = f2b(F[(kk*32 + qf*8 + j)*65 + nt*16 + lnf]);
            *(frag8*)(W2p + (((size_t)p*32 + slot)*64 + l)*8) = v;
        }
    }
}

// out = gelu(q @ W1_final) @ W2_final -> (B, N, H*D) f32.
// P1 uses SWAPPED MFMA operands (A=W1 frag, B=x frag) so C = z^T: per lane
// col = token, regs = 4 consecutive e' -> h stored to hl rows as packed
// ds_write_b64 (16 packed stores vs 64 scalar swizzled). Bit-identical math.
// P2 + staged full-line output stores unchanged.
__global__ __launch_bounds__(256) void k_apply(const float* __restrict__ qin,
                                               const short* __restrict__ W1p,
                                               const short* __restrict__ W2p,
                                               float* __restrict__ out){
    int p = blockIdx.x >> 5, mt = blockIdx.x & 31;
    int tid = threadIdx.x;
    int w = tid >> 6, lane = tid & 63, q = lane >> 4, ln = lane & 15;
    int m0 = mt*64;
    int b = p >> 4, h = p & 15;
    __shared__ __attribute__((aligned(16))) short hl[64*264];
    float* ol = (float*)hl;                      // reused as [64][68] f32
    const float* xbase = qin + ((size_t)p*NTOK + m0 + w*16 + ln)*DD;
    frag8 af[2];
    #pragma unroll
    for (int kk=0;kk<2;kk++){
        const float* xr = xbase + kk*32 + q*8;
        float4 u0 = *(const float4*)xr;
        float4 u1 = *(const float4*)(xr+4);
        frag8 a;
        a[0]=f2b(u0.x); a[1]=f2b(u0.y); a[2]=f2b(u0.z); a[3]=f2b(u0.w);
        a[4]=f2b(u1.x); a[5]=f2b(u1.y); a[6]=f2b(u1.z); a[7]=f2b(u1.w);
        af[kk]=a;
    }
    const short* w1b = W1p + ((size_t)p*32*64 + lane)*8;
    #pragma unroll
    for (int nt=0;nt<16;nt++){
        frag4f zc = {0.f,0.f,0.f,0.f};
        #pragma unroll
        for (int kk=0;kk<2;kk++){
            frag8 bfr = *(const frag8*)(w1b + (size_t)(nt*2+kk)*64*8);
            zc = MFMA(bfr, af[kk], zc);          // SWAPPED: C = z^T[e'][token]
        }
        // lane: token = m0+w*16+ln, e' = nt*16 + q*4 + r
        short4v hp;
        #pragma unroll
        for (int r=0;r<4;r++)
            hp[r] = f2b(gelu_f(zc[r]));
        *(short4v*)&hl[(w*16+ln)*264 + nt*16 + q*4] = hp;   // packed row write
    }
    __syncthreads();
    frag8 hfr[8];
    #pragma unroll
    for (int kk=0;kk<8;kk++)
        hfr[kk] = *(const frag8*)(&hl[(w*16+ln)*264 + kk*32 + q*8]);
    __syncthreads();   // all hl reads done before ol overwrite
    const short* w2b = W2p + ((size_t)p*32*64 + lane)*8;
    frag4f oc4[4];
    #pragma unroll
    for (int nt=0;nt<4;nt++){
        frag4f oc = {0.f,0.f,0.f,0.f};
        #pragma unroll
        for (int kk=0;kk<8;kk++){
            frag8 bfr = *(const frag8*)(w2b + (size_t)(nt*8+kk)*64*8);
            oc = MFMA(hfr[kk], bfr, oc);
        }
        oc4[nt] = oc;
    }
    #pragma unroll
    for (int nt=0;nt<4;nt++)
        #pragma unroll
        for (int r=0;r<4;r++)
            ol[(w*16+q*4+r)*68 + nt*16 + ln] = oc4[nt][r];
    __syncthreads();
    // cooperative write: 8 lanes x 16B = one full 128B line per row per instr
    size_t obase = ((size_t)b*NTOK + m0)*(HH*DD) + (size_t)h*DD;
    int c8 = tid & 7;
    #pragma unroll
    for (int pass=0; pass<2; pass++){
        int row = pass*32 + (tid>>3);
        #pragma unroll
        for (int u=0; u<2; u++){
            float4 vv = *(const float4*)&ol[row*68 + (c8 + u*8)*4];
            *(float4*)&out[obase + (size_t)row*(HH*DD) + (c8 + u*8)*4] = vv;
        }
    }
}

extern "C" void kernel_launch(void* const* d_in, const int* in_sizes, int n_in,
                              void* d_out, int out_size, void* d_ws, size_t ws_size,
                              hipStream_t stream) {
    (void)in_sizes; (void)n_in; (void)out_size; (void)ws_size;
    const float* q  = (const float*)d_in[0];
    const float* k  = (const float*)d_in[1];
    const float* v  = (const float*)d_in[2];
    const float* W1 = (const float*)d_in[3];
    const float* W2 = (const float*)d_in[4];
    float* out = (float*)d_out;

    // ws: P0 partials; later overlapped by W1p/W2p
    // (P0 is dead after the t=3 read, before k_castW writes).
    float* P0  = (float*)d_ws;                        // NP*2*32768 f32
    short* W1p = (short*)d_ws;                        // 2x NP*16384 bf16 (overlap P0)
    short* W2p = W1p + (size_t)NP*16384;

    // d_out scratch: M0, M1 masters + P1 partials.
    // All dead before k_apply overwrites d_out with the real output.
    float* M0 = (float*)d_out;                        // NP*32768 f32 (W1|W2)
    float* M1 = M0 + (size_t)NP*32768;
    float* P1 = M1 + (size_t)NP*32768;                // NP*2*32768 f32

    // iter t uses masters_{t-1} = Mold - partials_{t-1}; writes masters_{t-1} to Mnew
    // and its own dW_t partial to Pout.
    //                           kin vin  MoW1  MoW2                      Pin  Mnew Pout hIdx fold t
    k_step<<<256,1024,0,stream>>>(k, v,  W1,   W2,                        P0,  M1,  P0,  1,   0,  0);
    k_step<<<256,1024,0,stream>>>(k, v,  M1,   M1+(size_t)NP*16384,       P0,  M0,  P1,  0,   1,  1);
    k_step<<<256,1024,0,stream>>>(k, v,  M0,   M0+(size_t)NP*16384,       P1,  M1,  P0,  0,   1,  2);
    k_step<<<256,1024,0,stream>>>(k, v,  M1,   M1+(size_t)NP*16384,       P0,  M0,  P1,  0,   1,  3);
    // masters_3 = M0 - P1, folded inside k_castW (coalesced)
    k_castW<<<NP*2, 1024, 0, stream>>>(M0, P1, W1p, W2p);
    k_apply<<<NP*32, 256, 0, stream>>>(q, W1p, W2p, out);
}

// Round 8
// 473.483 us; speedup vs baseline: 1.2036x; 1.0571x over previous
//
#include <hip/hip_runtime.h>
#include <hip/hip_bf16.h>

typedef __hip_bfloat16 bf16;
typedef __attribute__((ext_vector_type(8))) short frag8;   // 8 bf16 = 4 VGPR
typedef __attribute__((ext_vector_type(4))) float frag4f;  // MFMA C/D
typedef __attribute__((ext_vector_type(4))) short short4v; // 8B packed store

#define BB 8
#define HH 16
#define NTOK 2048
#define DD 64
#define HID 256
#define NIT 4
#define CH 512
#define NP 128
#define INV_CD 3.0517578125e-05f  // 1/(CH*DD)

#define MFMA(a,b,c) __builtin_amdgcn_mfma_f32_16x16x32_bf16((a),(b),(c),0,0,0)

// XOR swizzle (k_step only): spreads 8-row-strided column reads across disjoint
// 8-bank windows (row stride 528B === 0 mod 128B otherwise -> 8-way conflict).
#define SW(row,col) ((col) ^ ((((row)>>3)&3)<<4))

__device__ __forceinline__ short f2b(float f){
    union { __hip_bfloat16 b; short s; } u;
    u.b = __float2bfloat16(f);
    return u.s;
}

// Fast tanh via hardware exp: t = 1 - 2/(e^{2u}+1). Stable at +/-inf.
__device__ __forceinline__ float tanh_fast(float u){
    float e = __expf(2.0f*u);
    return 1.0f - 2.0f/(e+1.0f);
}

__device__ __forceinline__ float gelu_f(float x){
    const float c0 = 0.7978845608028654f, c1 = 0.044715f;
    float u = c0*(x + c1*x*x*x);
    float t = tanh_fast(u);
    return 0.5f*x*(1.0f+t);
}

// Fused gelu value + grad: ONE tanh shared.
__device__ __forceinline__ void gelu_both(float x, float* hv, float* gp){
    const float c0 = 0.7978845608028654f, c1 = 0.044715f;
    float x2 = x*x;
    float u = c0*(x + c1*x2*x);
    float t = tanh_fast(u);
    *hv = 0.5f*x*(1.0f+t);
    *gp = 0.5f*(1.0f+t) + 0.5f*x*(1.0f-t*t)*c0*(1.0f+3.0f*c1*x2);
}

// One fused inner-loop iteration. Block = (pair p, token-half). 1024 threads,
// 16 waves (4 row-strips x 4 column-groups). hl/W2c XOR-swizzled (conflict-free
// strided column reads in P3/P4). __launch_bounds__(1024,4) pins the VGPR
// budget to 128 (prevents the round-4 64-VGPR spilling schedule).
// y loads hoisted into P1 (4 VGPR live range: HBM latency hides under MFMA+gelu).
__global__ __launch_bounds__(1024, 4) void k_step(
    const float* __restrict__ kin, const float* __restrict__ vin,
    const float* __restrict__ MoW1, const float* __restrict__ MoW2,
    const float* __restrict__ Pin,  float* __restrict__ Mnew,
    float* __restrict__ Pout, int hIdx, int fold, int t)
{
    int p = blockIdx.x >> 1, half = blockIdx.x & 1;
    int tid = threadIdx.x;
    int w = tid >> 6, lane = tid & 63, q = lane >> 4, ln = lane & 15;
    int s = w >> 2, ch = w & 3;   // row-strip (16 rows), column quarter

    // 156 KB total -> 1 block/CU
    __shared__ __attribute__((aligned(16))) short W1c[256*72];   // W1^T [e'][d]
    __shared__ __attribute__((aligned(16))) short W2c[64*264];   // W2^T [o][e'] (swz)
    __shared__ __attribute__((aligned(16))) short hl [64*264];   // h  [m][e'] (swz)
    __shared__ __attribute__((aligned(16))) short el [64*72];    // e  [m][o]
    __shared__ __attribute__((aligned(16))) short eTl[64*72];    // e^T [o][m]
    __shared__ __attribute__((aligned(16))) short dzTl[256*72];  // dz^T [e'][m]

    // ---- cast masters -> LDS bf16 (+ fold partials, + materialize Mnew) ----
    {
        int widx = hIdx ? (p & 15) : p;
        const float* w1o = MoW1 + (size_t)widx*16384;
        const float* w2o = MoW2 + (size_t)widx*16384;
        const float* pa = Pin + (size_t)p*32768;
        const float* pb = Pin + (size_t)(NP+p)*32768;
        float* mn1 = Mnew + (size_t)p*16384;
        float* mn2 = Mnew + (size_t)(NP+p)*16384;
        #pragma unroll 4
        for (int i=0;i<16;i++){
            int src = i*1024 + tid;
            float a = w1o[src];
            float b = w2o[src];
            if (fold){
                a -= pa[src] + pb[src];
                b -= pa[16384+src] + pb[16384+src];
            }
            if (half == 0){            // dedup: both halves compute identical a,b
                mn1[src] = a;
                mn2[src] = b;
            }
            W1c[(src & 255)*72  + (src >> 8)] = f2b(a);              // [e'][d]
            W2c[(src & 63)*264  + SW(src & 63, src >> 6)] = f2b(b);  // [o][e'] swz
        }
    }
    __syncthreads();

    frag4f dw1[4], dw2[4];
    #pragma unroll
    for (int i=0;i<4;i++){ frag4f zz = {0.f,0.f,0.f,0.f}; dw1[i]=zz; dw2[i]=zz; }

    size_t rowbase = (size_t)p*NTOK + (size_t)t*CH + (size_t)half*256;

    #pragma unroll 1
    for (int mt=0; mt<4; ++mt){
        int m0 = mt*64;

        // ---------- P1: z = x@W1 ; h=gelu(z)->hl ; zacc := gelu'(z) ----------
        frag8 af[2];
        {
            const float* xb = kin + (rowbase + m0 + s*16 + ln)*DD;
            #pragma unroll
            for (int kk=0;kk<2;kk++){
                const float* xr = xb + kk*32 + q*8;
                float4 u0 = *(const float4*)xr;
                float4 u1 = *(const float4*)(xr+4);
                frag8 a;
                a[0]=f2b(u0.x); a[1]=f2b(u0.y); a[2]=f2b(u0.z); a[3]=f2b(u0.w);
                a[4]=f2b(u1.x); a[5]=f2b(u1.y); a[6]=f2b(u1.z); a[7]=f2b(u1.w);
                af[kk]=a;
            }
        }
        // hoisted y for P2: 4 VGPR live across one barrier; latency hides
        // under P1's MFMA+gelu. (Safe now: VGPR budget pinned to 128.)
        float yv[4];
        #pragma unroll
        for (int r=0;r<4;r++)
            yv[r] = vin[(rowbase + m0 + s*16 + q*4 + r)*DD + ch*16 + ln];

        frag4f zacc[4];
        #pragma unroll
        for (int nti=0;nti<4;nti++){
            frag4f zc = {0.f,0.f,0.f,0.f};
            #pragma unroll
            for (int kk=0;kk<2;kk++){
                frag8 b = *(const frag8*)&W1c[((ch*4+nti)*16+ln)*72 + kk*32 + q*8];
                zc = MFMA(af[kk], b, zc);
            }
            zacc[nti] = zc;
        }
        #pragma unroll
        for (int nti=0;nti<4;nti++)
            #pragma unroll
            for (int r=0;r<4;r++){
                float hv, gp;
                gelu_both(zacc[nti][r], &hv, &gp);
                int row = s*16+q*4+r;
                hl[row*264 + SW(row, (ch*4+nti)*16 + ln)] = f2b(hv);
                zacc[nti][r] = gp;
            }
        __syncthreads();

        // ---------- P2: out = h@W2 ; e=(out-y)*s -> el,eTl ----------
        {
            frag8 hfr[8];
            #pragma unroll
            for (int kk=0;kk<8;kk++)
                hfr[kk] = *(const frag8*)&hl[(s*16+ln)*264 + SW(s*16+ln, kk*32 + q*8)];
            frag4f oc = {0.f,0.f,0.f,0.f};
            #pragma unroll
            for (int kk=0;kk<8;kk++){
                frag8 b = *(const frag8*)&W2c[(ch*16+ln)*264 + SW(ch*16+ln, kk*32 + q*8)];
                oc = MFMA(hfr[kk], b, oc);
            }
            short4v ep;
            #pragma unroll
            for (int r=0;r<4;r++){
                float e = (oc[r]-yv[r])*INV_CD;
                el[(s*16+q*4+r)*72 + ch*16 + ln] = f2b(e);
                ep[r] = f2b(e);
            }
            *(short4v*)&eTl[(ch*16+ln)*72 + s*16 + q*4] = ep;
        }
        __syncthreads();

        // ---------- P3: dz = (e@W2^T) * gelu'(z) -> dzTl ----------
        {
            frag8 efr[2];
            #pragma unroll
            for (int kk=0;kk<2;kk++)
                efr[kk] = *(const frag8*)&el[(s*16+ln)*72 + kk*32 + q*8];
            #pragma unroll
            for (int nti=0;nti<4;nti++){
                int nt = ch*4 + nti;
                frag4f dc = {0.f,0.f,0.f,0.f};
                #pragma unroll
                for (int kk=0;kk<2;kk++){
                    frag8 b;
                    #pragma unroll
                    for (int j=0;j<8;j++){
                        int row = kk*32+q*8+j;
                        b[j] = W2c[row*264 + SW(row, nt*16 + ln)];  // conflict-free
                    }
                    dc = MFMA(efr[kk], b, dc);
                }
                short4v dp;
                #pragma unroll
                for (int r=0;r<4;r++)
                    dp[r] = f2b(dc[r]*zacc[nti][r]);
                *(short4v*)&dzTl[(nt*16+ln)*72 + s*16 + q*4] = dp;
            }
        }
        __syncthreads();

        // ---------- P4: dW1 += x^T@dz ; dW2 += h^T@e ----------
        {
            #pragma unroll
            for (int kk2=0;kk2<2;kk2++){
                frag8 a;
                #pragma unroll
                for (int j=0;j<8;j++)
                    a[j] = f2b(kin[(rowbase + m0 + kk2*32 + q*8 + j)*DD + s*16 + ln]);
                #pragma unroll
                for (int nti=0;nti<4;nti++){
                    frag8 b = *(const frag8*)&dzTl[((ch*4+nti)*16+ln)*72 + kk2*32 + q*8];
                    dw1[nti] = MFMA(a, b, dw1[nti]);
                }
            }
            #pragma unroll
            for (int kk2=0;kk2<2;kk2++){
                frag8 a;
                #pragma unroll
                for (int j=0;j<8;j++){
                    int row = kk2*32+q*8+j;
                    a[j] = hl[row*264 + SW(row, w*16 + ln)];        // conflict-free
                }
                #pragma unroll
                for (int ot=0;ot<4;ot++){
                    frag8 b = *(const frag8*)&eTl[(ot*16+ln)*72 + kk2*32 + q*8];
                    dw2[ot] = MFMA(a, b, dw2[ot]);
                }
            }
        }
        __syncthreads();
    }

    // ---- write partial dW (non-atomic; disjoint per (half, p)) ----
    {
        float* pw1 = Pout + ((size_t)half*NP + p)*32768;
        float* pw2 = pw1 + 16384;
        #pragma unroll
        for (int nti=0;nti<4;nti++)
            #pragma unroll
            for (int r=0;r<4;r++)
                pw1[(s*16 + q*4 + r)*256 + (ch*4+nti)*16 + ln] = dw1[nti][r];
        #pragma unroll
        for (int ot=0;ot<4;ot++)
            #pragma unroll
            for (int r=0;r<4;r++)
                pw2[(w*16 + q*4 + r)*64 + ot*16 + ln] = dw2[ot][r];
    }
}

// Final masters = M0 - partialA - partialB. Coalesced: one block per
// (p, W1|W2); float4-coalesced fold into padded LDS f32 tile, then each thread
// emits 2 pre-swizzled bf16 fragment rows as single 16B stores.
__global__ __launch_bounds__(1024) void k_castW(const float* __restrict__ M0,
                                                const float* __restrict__ P1,
                                                short* __restrict__ W1p,
                                                short* __restrict__ W2p){
    int p = blockIdx.x >> 1, which = blockIdx.x & 1;
    int tid = threadIdx.x;
    __shared__ float F[256*65];    // W1 view: [64][257]; W2 view: [256][65]
    const float* m  = M0 + ((size_t)(which ? NP+p : p))*16384;
    const float* pa = P1 + (size_t)p*32768      + (size_t)which*16384;
    const float* pb = P1 + (size_t)(NP+p)*32768 + (size_t)which*16384;

    // coalesced fold: 4 float4 per thread
    #pragma unroll
    for (int i=0;i<4;i++){
        int idx4 = i*4096 + tid*4;
        float4 mv = *(const float4*)(m  + idx4);
        float4 av = *(const float4*)(pa + idx4);
        float4 bv = *(const float4*)(pb + idx4);
        float vv[4] = { mv.x-av.x-bv.x, mv.y-av.y-bv.y, mv.z-av.z-bv.z, mv.w-av.w-bv.w };
        if (which == 0){               // W1 [d=64][e'=256], pad 257
            int row = idx4 >> 8, col = idx4 & 255;
            #pragma unroll
            for (int e=0;e<4;e++) F[row*257 + col + e] = vv[e];
        } else {                       // W2 [e'=256][o=64], pad 65
            int row = idx4 >> 6, col = idx4 & 63;
            #pragma unroll
            for (int e=0;e<4;e++) F[row*65 + col + e] = vv[e];
        }
    }
    __syncthreads();

    // emit 2 fragment rows per thread (32 slots x 64 "lanes" = 2048)
    #pragma unroll
    for (int inst=0;inst<2;inst++){
        int fi = inst*1024 + tid;
        int slot = fi >> 6, l = fi & 63;
        int qf = l >> 4, lnf = l & 15;
        frag8 v;
        if (which == 0){               // W1p: elem j = W1[kk*32+qf*8+j][nt*16+lnf]
            int nt = slot >> 1, kk = slot & 1;
            #pragma unroll
            for (int j=0;j<8;j++)
                v[j] = f2b(F[(kk*32 + qf*8 + j)*257 + nt*16 + lnf]);
            *(frag8*)(W1p + (((size_t)p*32 + slot)*64 + l)*8) = v;
        } else {                       // W2p: elem j = W2[kk*32+qf*8+j][nt*16+lnf]
            int nt = slot >> 3, kk = slot & 7;
            #pragma unroll
            for (int j=0;j<8;j++)
                v[j] = f2b(F[(kk*32 + qf*8 + j)*65 + nt*16 + lnf]);
            *(frag8*)(W2p + (((size_t)p*32 + slot)*64 + l)*8) = v;
        }
    }
}

// out = gelu(q @ W1_final) @ W2_final -> (B, N, H*D) f32.
// Round-1 form (best measured: 80 us, 0.52M conflicts):
// scalar hl writes, plain b128 reads, direct global stores.
__global__ __launch_bounds__(256) void k_apply(const float* __restrict__ qin,
                                               const short* __restrict__ W1p,
                                               const short* __restrict__ W2p,
                                               float* __restrict__ out){
    int p = blockIdx.x >> 5, mt = blockIdx.x & 31;
    int tid = threadIdx.x;
    int w = tid >> 6, lane = tid & 63, q = lane >> 4, ln = lane & 15;
    int m0 = mt*64;
    int b = p >> 4, h = p & 15;
    __shared__ short hl[64*264];
    const float* xbase = qin + ((size_t)p*NTOK + m0 + w*16 + ln)*DD;
    frag8 af[2];
    #pragma unroll
    for (int kk=0;kk<2;kk++){
        const float* xr = xbase + kk*32 + q*8;
        float4 u0 = *(const float4*)xr;
        float4 u1 = *(const float4*)(xr+4);
        frag8 a;
        a[0]=f2b(u0.x); a[1]=f2b(u0.y); a[2]=f2b(u0.z); a[3]=f2b(u0.w);
        a[4]=f2b(u1.x); a[5]=f2b(u1.y); a[6]=f2b(u1.z); a[7]=f2b(u1.w);
        af[kk]=a;
    }
    const short* w1b = W1p + ((size_t)p*32*64 + lane)*8;
    #pragma unroll
    for (int nt=0;nt<16;nt++){
        frag4f zc = {0.f,0.f,0.f,0.f};
        #pragma unroll
        for (int kk=0;kk<2;kk++){
            frag8 bfr = *(const frag8*)(w1b + (size_t)(nt*2+kk)*64*8);
            zc = MFMA(af[kk], bfr, zc);
        }
        #pragma unroll
        for (int r=0;r<4;r++)
            hl[(w*16 + q*4 + r)*264 + nt*16 + ln] = f2b(gelu_f(zc[r]));
    }
    __syncthreads();
    frag8 hfr[8];
    #pragma unroll
    for (int kk=0;kk<8;kk++)
        hfr[kk] = *(const frag8*)(&hl[(w*16+ln)*264 + kk*32 + q*8]);
    const short* w2b = W2p + ((size_t)p*32*64 + lane)*8;
    #pragma unroll
    for (int nt=0;nt<4;nt++){
        frag4f oc = {0.f,0.f,0.f,0.f};
        #pragma unroll
        for (int kk=0;kk<8;kk++){
            frag8 bfr = *(const frag8*)(w2b + (size_t)(nt*8+kk)*64*8);
            oc = MFMA(hfr[kk], bfr, oc);
        }
        #pragma unroll
        for (int r=0;r<4;r++){
            int n = m0 + w*16 + q*4 + r;
            out[((size_t)b*NTOK + n)*(HH*DD) + h*DD + nt*16 + ln] = oc[r];
        }
    }
}

extern "C" void kernel_launch(void* const* d_in, const int* in_sizes, int n_in,
                              void* d_out, int out_size, void* d_ws, size_t ws_size,
                              hipStream_t stream) {
    (void)in_sizes; (void)n_in; (void)out_size; (void)ws_size;
    const float* q  = (const float*)d_in[0];
    const float* k  = (const float*)d_in[1];
    const float* v  = (const float*)d_in[2];
    const float* W1 = (const float*)d_in[3];
    const float* W2 = (const float*)d_in[4];
    float* out = (float*)d_out;

    // ws: P0 partials; later overlapped by W1p/W2p
    // (P0 is dead after the t=3 read, before k_castW writes).
    float* P0  = (float*)d_ws;                        // NP*2*32768 f32
    short* W1p = (short*)d_ws;                        // 2x NP*16384 bf16 (overlap P0)
    short* W2p = W1p + (size_t)NP*16384;

    // d_out scratch: M0, M1 masters + P1 partials.
    // All dead before k_apply overwrites d_out with the real output.
    float* M0 = (float*)d_out;                        // NP*32768 f32 (W1|W2)
    float* M1 = M0 + (size_t)NP*32768;
    float* P1 = M1 + (size_t)NP*32768;                // NP*2*32768 f32

    // iter t uses masters_{t-1} = Mold - partials_{t-1}; writes masters_{t-1} to Mnew
    // and its own dW_t partial to Pout.
    //                           kin vin  MoW1  MoW2                      Pin  Mnew Pout hIdx fold t
    k_step<<<256,1024,0,stream>>>(k, v,  W1,   W2,                        P0,  M1,  P0,  1,   0,  0);
    k_step<<<256,1024,0,stream>>>(k, v,  M1,   M1+(size_t)NP*16384,       P0,  M0,  P1,  0,   1,  1);
    k_step<<<256,1024,0,stream>>>(k, v,  M0,   M0+(size_t)NP*16384,       P1,  M1,  P0,  0,   1,  2);
    k_step<<<256,1024,0,stream>>>(k, v,  M1,   M1+(size_t)NP*16384,       P0,  M0,  P1,  0,   1,  3);
    // masters_3 = M0 - P1, folded inside k_castW (coalesced)
    k_castW<<<NP*2, 1024, 0, stream>>>(M0, P1, W1p, W2p);
    k_apply<<<NP*32, 256, 0, stream>>>(q, W1p, W2p, out);
}